// Round 2
// baseline (649.516 us; speedup 1.0000x reference)
//
#include <hip/hip_runtime.h>
#include <stdint.h>

#define T_SEQ   1500
#define NB      32
#define NH      8
#define SCALING 0.08838834764831845f   // 1/sqrt(128)

typedef __attribute__((ext_vector_type(8))) short short8;
typedef __attribute__((ext_vector_type(16))) float floatx16;

__device__ __forceinline__ uint16_t f2bf(float f) {
    uint32_t u = __float_as_uint(f);
    u += 0x7fffu + ((u >> 16) & 1u);   // round-to-nearest-even
    return (uint16_t)(u >> 16);
}
__device__ __forceinline__ float fast_tanh(float x) {
    return 1.f - 2.f / (__expf(2.f * x) + 1.f);
}
// enc_hs_len may arrive as int64 (ref declares jnp.int64) or int32.
__device__ __forceinline__ int get_len(const int* L, int b) {
    return (L[1] == 0) ? L[2 * b] : L[b];
}

// ---------------- enc fp32 -> bf16 (49,152,000 elems, 8/thread) ----------------
__global__ __launch_bounds__(256) void k_conv_enc(const float* __restrict__ in,
                                                  uint16_t* __restrict__ out) {
    int i = blockIdx.x * 256 + threadIdx.x;          // i in [0, 6,144,000)
    const float4* p = (const float4*)in + (size_t)i * 2;
    float4 a = p[0], b = p[1];
    uint4 r;
    r.x = (uint32_t)f2bf(a.x) | ((uint32_t)f2bf(a.y) << 16);
    r.y = (uint32_t)f2bf(a.z) | ((uint32_t)f2bf(a.w) << 16);
    r.z = (uint32_t)f2bf(b.x) | ((uint32_t)f2bf(b.y) << 16);
    r.w = (uint32_t)f2bf(b.z) | ((uint32_t)f2bf(b.w) << 16);
    ((uint4*)out)[i] = r;
}

// --- Wk (h,k,n) fp32 -> Bp: MFMA B-operand-native bf16 layout ---
// Bp[((h*128 + (k>>3))*128 + n)*8 + (k&7)] = Wk[h][k][n]
__global__ __launch_bounds__(128) void k_conv_wkB(const float* __restrict__ Wk,
                                                  uint16_t* __restrict__ Bp) {
    int h = blockIdx.x, g = blockIdx.y;              // g in [0,128)
    int n = threadIdx.x;                             // n in [0,128)
    const float* src = Wk + (size_t)h * 131072 + (size_t)g * 8 * 128 + n;
    uint16_t v[8];
#pragma unroll
    for (int e = 0; e < 8; ++e) v[e] = f2bf(src[(size_t)e * 128]);
    uint4 r;
    r.x = (uint32_t)v[0] | ((uint32_t)v[1] << 16);
    r.y = (uint32_t)v[2] | ((uint32_t)v[3] << 16);
    r.z = (uint32_t)v[4] | ((uint32_t)v[5] << 16);
    r.w = (uint32_t)v[6] | ((uint32_t)v[7] << 16);
    *(uint4*)(Bp + (((size_t)h * 128 + g) * 128 + n) * 8) = r;
}

// ---------------- q = tanh(dec_z @ Wq + bq); 1 (b,h) per block ----------------
__global__ __launch_bounds__(128) void k_q(const float* __restrict__ dec_z,
                                           const float* __restrict__ Wq,
                                           const float* __restrict__ bq,
                                           float* __restrict__ q_ws) {
    __shared__ float zs[1024];
    int b = blockIdx.x, h = blockIdx.y, tid = threadIdx.x;
    for (int i = tid; i < 1024; i += 128) zs[i] = dec_z[b * 1024 + i];
    __syncthreads();
    float acc = bq[h * 128 + tid];
    const float* wp = Wq + (size_t)h * 131072 + tid;
#pragma unroll 8
    for (int d = 0; d < 1024; ++d) acc += zs[d] * wp[(size_t)d * 128];
    q_ws[(b * 8 + h) * 128 + tid] = fast_tanh(acc);
}

// ------- big GEMM: e[b,h,t] = sum_dk tanh( (enc @ Wk[h])[t,dk] ) * q[b,h,dk] -------
// 128x128 tile, BK=32 (32 kt steps), 32x32x16 bf16 MFMA (2x2 frags/wave).
//
// OCCUPANCY is the lever this round: prior config was register-capped at 3
// waves/SIMD (76 VGPR + 64 acc-AGPR ~ 140 unified regs). BK=32 halves the
// per-kt B register buffer (br[2][2][2] = 32 VGPR, was 64) -> ~120 total regs
// -> 4 waves/SIMD; LDS = 4 x 8 KB = 32 KB -> 4 blocks/CU feasible.
//
// A: LDS 4-buffered via global_load_lds w=16 (XOR chunk swizzle, linear dest);
//    DMA(kt+2) issued at kt, drained by counted vmcnt at end of kt+1 -> two
//    compute phases + two barriers of latency cover.
// B: operand-native global loads prefetched one kt ahead into register dbuf;
//    retired lazily by compiler per-reg waits at MFMA use.
// Raw s_barrier so in-flight loads survive the barrier.
//
// vmcnt FIFO (per wave, issue order per kt: BLD(kt+1)x4 then DMA(kt+2)x2):
//   at end of compute(kt): [D(kt+1)x2, B(kt+1)x4, D(kt+2)x2]  (B(kt) retired
//   during compute by per-reg waits; D(kt) was older than B(kt) -> retired too)
//   vmcnt(6) retires exactly D(kt+1)  -> barrier(kt+1) publishes its LDS.
//   Tail: kt=30 -> vmcnt(4) retires D(31); kt=31 -> nothing (B(31) retired
//   by compiler). Prologue: [B0x4,D0x2,D1x2] -> vmcnt(2) before first barrier.
// Hazards: DMA(kt+2) writes buf[(kt+2)%4], last read at compute(kt-2), two
// barriers earlier -> safe. compute(kt) reads buf[kt%4]: own-portion drained
// by the end-of-(kt-1) vmcnt, cross-wave visibility by barrier(kt).
__global__ __launch_bounds__(256, 4) void k_gemm_e(const uint16_t* __restrict__ A,   // encb  M x 1024
                                                   const uint16_t* __restrict__ Bp,  // operand-native B
                                                   const float* __restrict__ q_ws,
                                                   float* __restrict__ e_ws) {
    __shared__ uint16_t As[4][128 * 32];   // 32 KB ; buf0 head reused as ered after k-loop

    const int tid = threadIdx.x;
    const int lane = tid & 63, wv = tid >> 6;
    const int hl = lane >> 5, la = lane & 31;

    const int idx = blockIdx.x;
    const int x = idx & 7;
    const int j = idx >> 3;
    int mt = x * 47 + (j >> 3);
    const int h = j & 7;
    if (mt > 374) mt = 374;                          // pad tile: duplicate of 374
    const int m_base = mt * 128;

    const int b0 = m_base / 1500;
    const int b1 = (m_base + 127) / 1500;

    const int wm = wv >> 1, wn = wv & 1;

    // q fragments in registers: cols wn*64 + la and +32, for batches b0 and b1
    const int c0 = wn * 64 + la;
    const float* qp0 = q_ws + (b0 * 8 + h) * 128;
    const float* qp1 = q_ws + (b1 * 8 + h) * 128;
    const float q00 = qp0[c0], q01 = qp0[c0 + 32];
    const float q10 = qp1[c0], q11 = qp1[c0 + 32];

    floatx16 acc[2][2];
#pragma unroll
    for (int i = 0; i < 2; ++i)
#pragma unroll
        for (int jj = 0; jj < 2; ++jj)
#pragma unroll
            for (int r = 0; r < 16; ++r) acc[i][jj][r] = 0.f;

    const char* Ab = (const char*)A;
    char* AsB = (char*)As;
    const short8* Bp8 = (const short8*)Bp + (size_t)h * 16384 + wn * 64 + la;

    short8 br[2][2][2];                              // B register double-buffer (32 VGPR)

#define DMA_KT(kt)                                                                   \
    {                                                                                \
        _Pragma("unroll")                                                            \
        for (int it = 0; it < 2; ++it) {                                             \
            int row = it * 64 + wv * 16 + (lane >> 2);                               \
            int c = (lane & 3) ^ ((lane >> 2) & 3);                                  \
            const char* ga = Ab + (size_t)(m_base + row) * 2048 + (kt) * 64 + c * 16; \
            char* ldsa = AsB + ((kt) & 3) * 8192 + it * 4096 + wv * 1024;            \
            __builtin_amdgcn_global_load_lds((const __attribute__((address_space(1))) void*)ga, \
                                             (__attribute__((address_space(3))) void*)ldsa, 16, 0, 0); \
        }                                                                            \
    }
#define BLD_KT(kt)                                                                   \
    {                                                                                \
        _Pragma("unroll")                                                            \
        for (int s = 0; s < 2; ++s) {                                                \
            const short8* bg = Bp8 + (size_t)((kt) * 4 + s * 2 + hl) * 128;          \
            br[(kt) & 1][s][0] = bg[0];                                              \
            br[(kt) & 1][s][1] = bg[32];                                             \
        }                                                                            \
    }

    BLD_KT(0);                                       // oldest in queue (retired before loop)
    DMA_KT(0);
    DMA_KT(1);
    __builtin_amdgcn_s_waitcnt(0x0f72);              // vmcnt(2): B(0)+D(0) retired, D(1) in flight

#pragma unroll
    for (int kt = 0; kt < 32; ++kt) {
        __builtin_amdgcn_s_barrier();                // publishes D(kt); in-flight loads survive
        if (kt < 31) BLD_KT(kt + 1);                 // B regs for kt+1 (lazy retire)
        if (kt < 30) DMA_KT(kt + 2);                 // into buf[(kt+2)%4]
#pragma unroll
        for (int s = 0; s < 2; ++s) {                // compute kt
            short8 af[2];
#pragma unroll
            for (int i = 0; i < 2; ++i) {
                int r = wm * 64 + i * 32 + la;
                int slot = (s * 2 + hl) ^ (r & 3);
                af[i] = *(const short8*)(AsB + (kt & 3) * 8192 + r * 64 + slot * 16);
            }
#pragma unroll
            for (int i = 0; i < 2; ++i)
#pragma unroll
                for (int jj = 0; jj < 2; ++jj)
                    acc[i][jj] = __builtin_amdgcn_mfma_f32_32x32x16_bf16(af[i], br[kt & 1][s][jj], acc[i][jj], 0, 0, 0);
        }
        if (kt < 30)
            __builtin_amdgcn_s_waitcnt(0x0f76);      // vmcnt(6): retire D(kt+1) only
        else if (kt == 30)
            __builtin_amdgcn_s_waitcnt(0x0f74);      // vmcnt(4): retire D(31)
    }
#undef DMA_KT
#undef BLD_KT

    __syncthreads();                                 // all As reads done; reuse As as ered
    float (*ered)[2] = (float(*)[2])AsB;             // [128][2]

    // epilogue: e_row = sum_col tanh(k) * q[b(row), col]
    // C/D layout 32x32: col = la, row = (rg&3) + 8*(rg>>2) + 4*hl
    const int lim = (b0 + 1) * 1500 - m_base;        // rows >= lim belong to b1
#pragma unroll
    for (int i = 0; i < 2; ++i) {
#pragma unroll
        for (int rg = 0; rg < 16; ++rg) {
            int rowl = wm * 64 + i * 32 + (rg & 3) + 8 * (rg >> 2) + 4 * hl;
            bool second = (rowl >= lim);
            float qa = second ? q10 : q00;
            float qb = second ? q11 : q01;
            float es = fast_tanh(acc[i][0][rg]) * qa + fast_tanh(acc[i][1][rg]) * qb;
            es += __shfl_xor(es, 1);
            es += __shfl_xor(es, 2);
            es += __shfl_xor(es, 4);
            es += __shfl_xor(es, 8);
            es += __shfl_xor(es, 16);
            if (la == 0) ered[rowl][wn] = es;
        }
    }
    __syncthreads();
    if (tid < 128) {
        int rg = m_base + tid;
        int b = rg / 1500, t = rg - b * 1500;
        e_ws[(b * 8 + h) * 1500 + t] = ered[tid][0] + ered[tid][1];
    }
}

// ---------------- masked softmax over t; writes w (an output) ----------------
__global__ __launch_bounds__(256) void k_softmax(const float* __restrict__ e_ws,
                                                 const int* __restrict__ Lp,
                                                 float* __restrict__ w_out) {
    __shared__ float red[4], red2[4];
    int bh = blockIdx.x, tid = threadIdx.x;
    int len = get_len(Lp, bh >> 3);
    const float* e = e_ws + (size_t)bh * 1500;
    float mx = -1e30f;
    for (int t = tid; t < len; t += 256) mx = fmaxf(mx, e[t]);
#pragma unroll
    for (int o = 1; o < 64; o <<= 1) mx = fmaxf(mx, __shfl_xor(mx, o));
    if ((tid & 63) == 0) red[tid >> 6] = mx;
    __syncthreads();
    mx = fmaxf(fmaxf(red[0], red[1]), fmaxf(red[2], red[3]));
    float s = 0.f;
    for (int t = tid; t < len; t += 256) s += __expf(SCALING * (e[t] - mx));
#pragma unroll
    for (int o = 1; o < 64; o <<= 1) s += __shfl_xor(s, o);
    if ((tid & 63) == 0) red2[tid >> 6] = s;
    __syncthreads();
    float inv = 1.f / (red2[0] + red2[1] + red2[2] + red2[3]);
    for (int t = tid; t < 1500; t += 256) {
        float wv = (t < len) ? __expf(SCALING * (e[t] - mx)) * inv : 0.f;
        w_out[(size_t)bh * 1500 + t] = wv;
    }
}

// -------- s[b,h,d] = sum_t w[b,h,t]*enc[b,t,d]; partials over 8 t-parts --------
__global__ __launch_bounds__(256) void k_wsum(const uint16_t* __restrict__ encb,
                                              const float* __restrict__ w,
                                              const int* __restrict__ Lp,
                                              float* __restrict__ s_part) {
    __shared__ float ws_[8][128];
    int dt = blockIdx.x, b = blockIdx.y, p = blockIdx.z;
    int tid = threadIdx.x;
    int len = get_len(Lp, b);
    int t0 = p * 188;
    int t1 = min(min(1500, t0 + 188), len);
    int d0 = (dt * 256 + tid) * 2;
    float a0[8], a1[8];
#pragma unroll
    for (int h = 0; h < 8; ++h) { a0[h] = 0.f; a1[h] = 0.f; }
    for (int tc = t0; tc < t1; tc += 128) {
        int cl = min(128, t1 - tc);
        __syncthreads();
#pragma unroll
        for (int u = 0; u < 4; ++u) {
            int idx = u * 256 + tid, hh = idx >> 7, tl = idx & 127;
            ws_[hh][tl] = (tl < cl) ? w[(size_t)(b * 8 + hh) * 1500 + tc + tl] : 0.f;
        }
        __syncthreads();
        const uint16_t* ep = encb + ((size_t)b * 1500 + tc) * 1024 + d0;
        for (int tl = 0; tl < cl; ++tl) {
            uint32_t u = *(const uint32_t*)(ep + (size_t)tl * 1024);
            float e0 = __uint_as_float(u << 16);
            float e1 = __uint_as_float(u & 0xffff0000u);
#pragma unroll
            for (int h = 0; h < 8; ++h) {
                float wv = ws_[h][tl];
                a0[h] += wv * e0; a1[h] += wv * e1;
            }
        }
    }
#pragma unroll
    for (int h = 0; h < 8; ++h) {
        float2 v = make_float2(a0[h], a1[h]);
        *(float2*)&s_part[(((size_t)p * 32 + b) * 8 + h) * 1024 + d0] = v;
    }
}

// ---------------- c[b,h,:] = (sum_p s_part) @ Wv[h]; 1 (b,h) per block ----------------
__global__ __launch_bounds__(128) void k_cv(const float* __restrict__ s_part,
                                            const float* __restrict__ Wv,
                                            float* __restrict__ c_ws) {
    __shared__ float sv[1024];
    int b = blockIdx.x, h = blockIdx.y, tid = threadIdx.x;
    for (int i = tid; i < 1024; i += 128) {
        float acc = 0.f;
#pragma unroll
        for (int p = 0; p < 8; ++p)
            acc += s_part[(((size_t)p * 32 + b) * 8 + h) * 1024 + i];
        sv[i] = acc;
    }
    __syncthreads();
    float acc = 0.f;
    const float* wp = Wv + (size_t)h * 131072 + tid;
#pragma unroll 8
    for (int d = 0; d < 1024; ++d) acc += sv[d] * wp[(size_t)d * 128];
    c_ws[(b * 8 + h) * 128 + tid] = acc;
}

// ---------------- out = c.reshape(B,1024) @ Wo; 1 (nt,b) per block ----------------
__global__ __launch_bounds__(128) void k_out(const float* __restrict__ c_ws,
                                             const float* __restrict__ Wo,
                                             float* __restrict__ outp) {
    __shared__ float cs[1024];
    int nt = blockIdx.x, b = blockIdx.y, tid = threadIdx.x;
    for (int i = tid; i < 1024; i += 128) cs[i] = c_ws[b * 1024 + i];
    __syncthreads();
    float acc = 0.f;
    const float* wp = Wo + nt * 128 + tid;
#pragma unroll 8
    for (int m = 0; m < 1024; ++m) acc += cs[m] * wp[(size_t)m * 1024];
    outp[(size_t)b * 1024 + nt * 128 + tid] = acc;
}

extern "C" void kernel_launch(void* const* d_in, const int* in_sizes, int n_in,
                              void* d_out, int out_size, void* d_ws, size_t ws_size,
                              hipStream_t stream) {
    const float* enc   = (const float*)d_in[0];
    const int*   lens  = (const int*)d_in[1];
    const float* dec_z = (const float*)d_in[2];
    const float* Wq    = (const float*)d_in[3];
    const float* bq    = (const float*)d_in[4];
    const float* Wk    = (const float*)d_in[5];
    const float* Wv    = (const float*)d_in[6];
    const float* Wo    = (const float*)d_in[7];
    float* outp  = (float*)d_out;           // (32,1024)
    float* w_out = outp + 32768;            // (32,8,1500)

    char* ws = (char*)d_ws;
    uint16_t* encb   = (uint16_t*)ws;                    //  98,304,000 B
    uint16_t* Bp     = (uint16_t*)(ws + 98304000);       //   2,097,152 B
    float*    q_ws   = (float*)(ws + 100401152);         //     131,072 B
    float*    e_ws   = (float*)(ws + 100532224);         //   1,536,000 B
    float*    s_part = (float*)(ws + 102068224);         //   8,388,608 B
    float*    c_ws   = (float*)(ws + 110456832);         //     131,072 B  (end 110,587,904)
    if (ws_size < 110587904) return;

    k_conv_enc<<<24000, 256, 0, stream>>>(enc, encb);
    k_conv_wkB<<<dim3(8, 128), 128, 0, stream>>>(Wk, Bp);
    k_q<<<dim3(32, 8), 128, 0, stream>>>(dec_z, Wq, bq, q_ws);
    k_gemm_e<<<3008, 256, 0, stream>>>(encb, Bp, q_ws, e_ws);
    k_softmax<<<256, 256, 0, stream>>>(e_ws, lens, w_out);
    k_wsum<<<dim3(2, 32, 8), 256, 0, stream>>>(encb, w_out, lens, s_part);
    k_cv<<<dim3(32, 8), 128, 0, stream>>>(s_part, Wv, c_ws);
    k_out<<<dim3(8, 32), 128, 0, stream>>>(c_ws, Wo, outp);
}

// Round 3
// 631.653 us; speedup vs baseline: 1.0283x; 1.0283x over previous
//
#include <hip/hip_runtime.h>
#include <stdint.h>

#define T_SEQ   1500
#define NB      32
#define NH      8
#define SCALING 0.08838834764831845f   // 1/sqrt(128)

typedef __attribute__((ext_vector_type(8))) short short8;
typedef __attribute__((ext_vector_type(16))) float floatx16;

__device__ __forceinline__ uint16_t f2bf(float f) {
    uint32_t u = __float_as_uint(f);
    u += 0x7fffu + ((u >> 16) & 1u);   // round-to-nearest-even
    return (uint16_t)(u >> 16);
}
__device__ __forceinline__ float fast_tanh(float x) {
    return 1.f - 2.f / (__expf(2.f * x) + 1.f);
}
// enc_hs_len may arrive as int64 (ref declares jnp.int64) or int32.
__device__ __forceinline__ int get_len(const int* L, int b) {
    return (L[1] == 0) ? L[2 * b] : L[b];
}

// ---------------- enc fp32 -> bf16 (49,152,000 elems, 8/thread) ----------------
__global__ __launch_bounds__(256) void k_conv_enc(const float* __restrict__ in,
                                                  uint16_t* __restrict__ out) {
    int i = blockIdx.x * 256 + threadIdx.x;          // i in [0, 6,144,000)
    const float4* p = (const float4*)in + (size_t)i * 2;
    float4 a = p[0], b = p[1];
    uint4 r;
    r.x = (uint32_t)f2bf(a.x) | ((uint32_t)f2bf(a.y) << 16);
    r.y = (uint32_t)f2bf(a.z) | ((uint32_t)f2bf(a.w) << 16);
    r.z = (uint32_t)f2bf(b.x) | ((uint32_t)f2bf(b.y) << 16);
    r.w = (uint32_t)f2bf(b.z) | ((uint32_t)f2bf(b.w) << 16);
    ((uint4*)out)[i] = r;
}

// --- Wk (h,k,n) fp32 -> Bp: MFMA B-operand-native bf16 layout ---
// Bp[((h*128 + (k>>3))*128 + n)*8 + (k&7)] = Wk[h][k][n]
__global__ __launch_bounds__(128) void k_conv_wkB(const float* __restrict__ Wk,
                                                  uint16_t* __restrict__ Bp) {
    int h = blockIdx.x, g = blockIdx.y;              // g in [0,128)
    int n = threadIdx.x;                             // n in [0,128)
    const float* src = Wk + (size_t)h * 131072 + (size_t)g * 8 * 128 + n;
    uint16_t v[8];
#pragma unroll
    for (int e = 0; e < 8; ++e) v[e] = f2bf(src[(size_t)e * 128]);
    uint4 r;
    r.x = (uint32_t)v[0] | ((uint32_t)v[1] << 16);
    r.y = (uint32_t)v[2] | ((uint32_t)v[3] << 16);
    r.z = (uint32_t)v[4] | ((uint32_t)v[5] << 16);
    r.w = (uint32_t)v[6] | ((uint32_t)v[7] << 16);
    *(uint4*)(Bp + (((size_t)h * 128 + g) * 128 + n) * 8) = r;
}

// ---------------- q = tanh(dec_z @ Wq + bq); 1 (b,h) per block ----------------
__global__ __launch_bounds__(128) void k_q(const float* __restrict__ dec_z,
                                           const float* __restrict__ Wq,
                                           const float* __restrict__ bq,
                                           float* __restrict__ q_ws) {
    __shared__ float zs[1024];
    int b = blockIdx.x, h = blockIdx.y, tid = threadIdx.x;
    for (int i = tid; i < 1024; i += 128) zs[i] = dec_z[b * 1024 + i];
    __syncthreads();
    float acc = bq[h * 128 + tid];
    const float* wp = Wq + (size_t)h * 131072 + tid;
#pragma unroll 8
    for (int d = 0; d < 1024; ++d) acc += zs[d] * wp[(size_t)d * 128];
    q_ws[(b * 8 + h) * 128 + tid] = fast_tanh(acc);
}

// ------- big GEMM: e[b,h,t] = sum_dk tanh( (enc @ Wk[h])[t,dk] ) * q[b,h,dk] -------
// N per head is only 128, so a 128x128 tile re-reads A once per head (8x).
// THIS ROUND: 2 heads per block (128 rows x 256 cols), 512 thr / 8 waves
// (2 m-halves x 4 n-quarters; head = quarter>>1). A staged ONCE serves both
// heads -> A DMA traffic per FLOP halves. B (2 MB) stays L2-resident per XCD.
//
// LDS swizzle fix (R2 regression: 18.5M bank-conflict cycles): pair-of-rows
// XOR. Storage: chunk j=(r&1)*4+u (u = 16B chunk in row, k-dir) of row-pair
// p=r>>1 lives at byte (p*128 + (j^(p&7))*16). For any fixed (s,hl) the 32
// lanes' ds_read_b128 covers all 32 banks once per 8 lanes -> conflict-free.
// global_load_lds writes LINEAR LDS (wave base + lane*16), so the permutation
// is applied to the per-lane GLOBAL source address (pre-swizzled source):
//   g=lane>>3, l=lane&7, j=l^g -> row wv*16+2g+(j>>2), chunk u=j&3.
// Per-row 4 chunks stay a contiguous 64B segment -> coalescing preserved.
//
// Pipeline (unchanged shape): 4-deep LDS buffers, BK=32; DMA(kt+2) issued at
// kt, drained by counted vmcnt at end of kt+1 (two compute phases + two
// barriers of cover). B prefetched one kt ahead into register dbuf. Raw
// s_barrier so in-flight loads survive.
// vmcnt FIFO (per wave, 5 loads/kt: BLD x4 then DMA x1):
//   end of compute(kt): [D(kt+1)x1, B(kt+1)x4, D(kt+2)x1] -> vmcnt(5)
//   retires exactly D(kt+1). Prologue: [B0x4,D0,D1] -> vmcnt(1). Tail:
//   kt=30 -> vmcnt(4) retires D(31); kt=31 -> nothing (reg-dep retires B).
// Hazards: DMA(kt+2) writes buf[(kt+2)&3], last read compute(kt-2), two
// barriers ago. compute(kt) reads buf[kt&3]: own drain end of kt-1, cross-
// wave visibility via barrier(kt).
__global__ __launch_bounds__(512, 4) void k_gemm_e(const uint16_t* __restrict__ A,   // encb  M x 1024
                                                   const uint16_t* __restrict__ Bp,  // operand-native B
                                                   const float* __restrict__ q_ws,
                                                   float* __restrict__ e_ws) {
    __shared__ uint16_t As[4][128 * 32];   // 32 KB ; buf0 head reused as ered after k-loop

    const int tid = threadIdx.x;
    const int lane = tid & 63, wv = tid >> 6;        // 8 waves
    const int hl = lane >> 5, la = lane & 31;

    // grid: 1504 = 8 XCD-groups x 188; mt in [0,374], hpair in [0,3]
    const int idx = blockIdx.x;
    const int x = idx & 7;
    const int j = idx >> 3;                          // 0..187
    int mt = x * 47 + (j >> 2);
    const int hpair = j & 3;
    if (mt > 374) mt = 374;                          // pad tile: duplicate of 374
    const int m_base = mt * 128;

    const int b0 = m_base / 1500;
    const int b1 = (m_base + 127) / 1500;

    const int wm = wv & 1;                           // m-half
    const int wq = wv >> 1;                          // n-quarter 0..3
    const int h = hpair * 2 + (wq >> 1);             // this wave's head
    const int wn = wq & 1;                           // n-half within head

    // q fragments in registers: cols wn*64 + la and +32, batches b0 and b1
    const int c0 = wn * 64 + la;
    const float* qp0 = q_ws + (b0 * 8 + h) * 128;
    const float* qp1 = q_ws + (b1 * 8 + h) * 128;
    const float q00 = qp0[c0], q01 = qp0[c0 + 32];
    const float q10 = qp1[c0], q11 = qp1[c0 + 32];

    floatx16 acc[2][2];
#pragma unroll
    for (int i = 0; i < 2; ++i)
#pragma unroll
        for (int jj = 0; jj < 2; ++jj)
#pragma unroll
            for (int r = 0; r < 16; ++r) acc[i][jj][r] = 0.f;

    const char* Ab = (const char*)A;
    char* AsB = (char*)As;
    const short8* Bp8 = (const short8*)Bp + (size_t)h * 16384 + wn * 64 + la;

    short8 br[2][2][2];                              // B register double-buffer (32 VGPR)

    // DMA source pre-swizzle (per-lane constants, hoisted):
    const int dg = lane >> 3;                        // 0..7
    const int dj = (lane & 7) ^ dg;                  // chunk permutation
    const int drow = wv * 16 + 2 * dg + (dj >> 2);   // 0..127
    const int du = dj & 3;                           // 16B chunk within kt's 64B
    const char* dma_g0 = Ab + (size_t)(m_base + drow) * 2048 + du * 16;

#define DMA_KT(kt)                                                                   \
    {                                                                                \
        const char* ga = dma_g0 + (kt) * 64;                                         \
        char* ldsa = AsB + ((kt) & 3) * 8192 + wv * 1024;                            \
        __builtin_amdgcn_global_load_lds((const __attribute__((address_space(1))) void*)ga, \
                                         (__attribute__((address_space(3))) void*)ldsa, 16, 0, 0); \
    }
#define BLD_KT(kt)                                                                   \
    {                                                                                \
        _Pragma("unroll")                                                            \
        for (int s = 0; s < 2; ++s) {                                                \
            const short8* bg = Bp8 + (size_t)((kt) * 4 + s * 2 + hl) * 128;          \
            br[(kt) & 1][s][0] = bg[0];                                              \
            br[(kt) & 1][s][1] = bg[32];                                             \
        }                                                                            \
    }

    BLD_KT(0);                                       // oldest in queue
    DMA_KT(0);
    DMA_KT(1);
    __builtin_amdgcn_s_waitcnt(0x0f71);              // vmcnt(1): B(0)+D(0) retired, D(1) in flight

#pragma unroll
    for (int kt = 0; kt < 32; ++kt) {
        __builtin_amdgcn_s_barrier();                // publishes D(kt); in-flight loads survive
        if (kt < 31) BLD_KT(kt + 1);                 // B regs for kt+1 (lazy retire)
        if (kt < 30) DMA_KT(kt + 2);                 // into buf[(kt+2)&3]
#pragma unroll
        for (int s = 0; s < 2; ++s) {                // compute kt
            short8 af[2];
#pragma unroll
            for (int i = 0; i < 2; ++i) {
                int r = wm * 64 + i * 32 + la;       // row this lane reads
                int p = r >> 1;
                int jsl = (((r & 1) << 2) + s * 2 + hl) ^ (p & 7);
                af[i] = *(const short8*)(AsB + (kt & 3) * 8192 + p * 128 + jsl * 16);
            }
#pragma unroll
            for (int i = 0; i < 2; ++i)
#pragma unroll
                for (int jj = 0; jj < 2; ++jj)
                    acc[i][jj] = __builtin_amdgcn_mfma_f32_32x32x16_bf16(af[i], br[kt & 1][s][jj], acc[i][jj], 0, 0, 0);
        }
        if (kt < 30)
            __builtin_amdgcn_s_waitcnt(0x0f75);      // vmcnt(5): retire D(kt+1) only
        else if (kt == 30)
            __builtin_amdgcn_s_waitcnt(0x0f74);      // vmcnt(4): retire D(31)
    }
#undef DMA_KT
#undef BLD_KT

    __syncthreads();                                 // all As reads done; reuse As as ered
    float (*ered)[128][2] = (float(*)[128][2])AsB;   // [head_local][row][wn]

    // epilogue: e_row = sum_col tanh(k) * q[b(row), col]
    // C/D layout 32x32: col = la, row = (rg&3) + 8*(rg>>2) + 4*hl
    const int lim = (b0 + 1) * 1500 - m_base;        // rows >= lim belong to b1
    const int hloc = wq >> 1;
#pragma unroll
    for (int i = 0; i < 2; ++i) {
#pragma unroll
        for (int rg = 0; rg < 16; ++rg) {
            int rowl = wm * 64 + i * 32 + (rg & 3) + 8 * (rg >> 2) + 4 * hl;
            bool second = (rowl >= lim);
            float qa = second ? q10 : q00;
            float qb = second ? q11 : q01;
            float es = fast_tanh(acc[i][0][rg]) * qa + fast_tanh(acc[i][1][rg]) * qb;
            es += __shfl_xor(es, 1);
            es += __shfl_xor(es, 2);
            es += __shfl_xor(es, 4);
            es += __shfl_xor(es, 8);
            es += __shfl_xor(es, 16);
            if (la == 0) ered[hloc][rowl][wn] = es;
        }
    }
    __syncthreads();
    if (tid < 256) {
        int hloc2 = tid >> 7, rowl = tid & 127;
        int rg = m_base + rowl;
        int b = rg / 1500, t = rg - b * 1500;
        e_ws[(b * 8 + hpair * 2 + hloc2) * 1500 + t] = ered[hloc2][rowl][0] + ered[hloc2][rowl][1];
    }
}

// ---------------- masked softmax over t; writes w (an output) ----------------
__global__ __launch_bounds__(256) void k_softmax(const float* __restrict__ e_ws,
                                                 const int* __restrict__ Lp,
                                                 float* __restrict__ w_out) {
    __shared__ float red[4], red2[4];
    int bh = blockIdx.x, tid = threadIdx.x;
    int len = get_len(Lp, bh >> 3);
    const float* e = e_ws + (size_t)bh * 1500;
    float mx = -1e30f;
    for (int t = tid; t < len; t += 256) mx = fmaxf(mx, e[t]);
#pragma unroll
    for (int o = 1; o < 64; o <<= 1) mx = fmaxf(mx, __shfl_xor(mx, o));
    if ((tid & 63) == 0) red[tid >> 6] = mx;
    __syncthreads();
    mx = fmaxf(fmaxf(red[0], red[1]), fmaxf(red[2], red[3]));
    float s = 0.f;
    for (int t = tid; t < len; t += 256) s += __expf(SCALING * (e[t] - mx));
#pragma unroll
    for (int o = 1; o < 64; o <<= 1) s += __shfl_xor(s, o);
    if ((tid & 63) == 0) red2[tid >> 6] = s;
    __syncthreads();
    float inv = 1.f / (red2[0] + red2[1] + red2[2] + red2[3]);
    for (int t = tid; t < 1500; t += 256) {
        float wv = (t < len) ? __expf(SCALING * (e[t] - mx)) * inv : 0.f;
        w_out[(size_t)bh * 1500 + t] = wv;
    }
}

// -------- s[b,h,d] = sum_t w[b,h,t]*enc[b,t,d]; partials over 8 t-parts --------
__global__ __launch_bounds__(256) void k_wsum(const uint16_t* __restrict__ encb,
                                              const float* __restrict__ w,
                                              const int* __restrict__ Lp,
                                              float* __restrict__ s_part) {
    __shared__ float ws_[8][128];
    int dt = blockIdx.x, b = blockIdx.y, p = blockIdx.z;
    int tid = threadIdx.x;
    int len = get_len(Lp, b);
    int t0 = p * 188;
    int t1 = min(min(1500, t0 + 188), len);
    int d0 = (dt * 256 + tid) * 2;
    float a0[8], a1[8];
#pragma unroll
    for (int h = 0; h < 8; ++h) { a0[h] = 0.f; a1[h] = 0.f; }
    for (int tc = t0; tc < t1; tc += 128) {
        int cl = min(128, t1 - tc);
        __syncthreads();
#pragma unroll
        for (int u = 0; u < 4; ++u) {
            int idx = u * 256 + tid, hh = idx >> 7, tl = idx & 127;
            ws_[hh][tl] = (tl < cl) ? w[(size_t)(b * 8 + hh) * 1500 + tc + tl] : 0.f;
        }
        __syncthreads();
        const uint16_t* ep = encb + ((size_t)b * 1500 + tc) * 1024 + d0;
        for (int tl = 0; tl < cl; ++tl) {
            uint32_t u = *(const uint32_t*)(ep + (size_t)tl * 1024);
            float e0 = __uint_as_float(u << 16);
            float e1 = __uint_as_float(u & 0xffff0000u);
#pragma unroll
            for (int h = 0; h < 8; ++h) {
                float wv = ws_[h][tl];
                a0[h] += wv * e0; a1[h] += wv * e1;
            }
        }
    }
#pragma unroll
    for (int h = 0; h < 8; ++h) {
        float2 v = make_float2(a0[h], a1[h]);
        *(float2*)&s_part[(((size_t)p * 32 + b) * 8 + h) * 1024 + d0] = v;
    }
}

// ---------------- c[b,h,:] = (sum_p s_part) @ Wv[h]; 1 (b,h) per block ----------------
__global__ __launch_bounds__(128) void k_cv(const float* __restrict__ s_part,
                                            const float* __restrict__ Wv,
                                            float* __restrict__ c_ws) {
    __shared__ float sv[1024];
    int b = blockIdx.x, h = blockIdx.y, tid = threadIdx.x;
    for (int i = tid; i < 1024; i += 128) {
        float acc = 0.f;
#pragma unroll
        for (int p = 0; p < 8; ++p)
            acc += s_part[(((size_t)p * 32 + b) * 8 + h) * 1024 + i];
        sv[i] = acc;
    }
    __syncthreads();
    float acc = 0.f;
    const float* wp = Wv + (size_t)h * 131072 + tid;
#pragma unroll 8
    for (int d = 0; d < 1024; ++d) acc += sv[d] * wp[(size_t)d * 128];
    c_ws[(b * 8 + h) * 128 + tid] = acc;
}

// ---------------- out = c.reshape(B,1024) @ Wo; 1 (nt,b) per block ----------------
__global__ __launch_bounds__(128) void k_out(const float* __restrict__ c_ws,
                                             const float* __restrict__ Wo,
                                             float* __restrict__ outp) {
    __shared__ float cs[1024];
    int nt = blockIdx.x, b = blockIdx.y, tid = threadIdx.x;
    for (int i = tid; i < 1024; i += 128) cs[i] = c_ws[b * 1024 + i];
    __syncthreads();
    float acc = 0.f;
    const float* wp = Wo + nt * 128 + tid;
#pragma unroll 8
    for (int m = 0; m < 1024; ++m) acc += cs[m] * wp[(size_t)m * 1024];
    outp[(size_t)b * 1024 + nt * 128 + tid] = acc;
}

extern "C" void kernel_launch(void* const* d_in, const int* in_sizes, int n_in,
                              void* d_out, int out_size, void* d_ws, size_t ws_size,
                              hipStream_t stream) {
    const float* enc   = (const float*)d_in[0];
    const int*   lens  = (const int*)d_in[1];
    const float* dec_z = (const float*)d_in[2];
    const float* Wq    = (const float*)d_in[3];
    const float* bq    = (const float*)d_in[4];
    const float* Wk    = (const float*)d_in[5];
    const float* Wv    = (const float*)d_in[6];
    const float* Wo    = (const float*)d_in[7];
    float* outp  = (float*)d_out;           // (32,1024)
    float* w_out = outp + 32768;            // (32,8,1500)

    char* ws = (char*)d_ws;
    uint16_t* encb   = (uint16_t*)ws;                    //  98,304,000 B
    uint16_t* Bp     = (uint16_t*)(ws + 98304000);       //   2,097,152 B
    float*    q_ws   = (float*)(ws + 100401152);         //     131,072 B
    float*    e_ws   = (float*)(ws + 100532224);         //   1,536,000 B
    float*    s_part = (float*)(ws + 102068224);         //   8,388,608 B
    float*    c_ws   = (float*)(ws + 110456832);         //     131,072 B  (end 110,587,904)
    if (ws_size < 110587904) return;

    k_conv_enc<<<24000, 256, 0, stream>>>(enc, encb);
    k_conv_wkB<<<dim3(8, 128), 128, 0, stream>>>(Wk, Bp);
    k_q<<<dim3(32, 8), 128, 0, stream>>>(dec_z, Wq, bq, q_ws);
    k_gemm_e<<<1504, 512, 0, stream>>>(encb, Bp, q_ws, e_ws);
    k_softmax<<<256, 256, 0, stream>>>(e_ws, lens, w_out);
    k_wsum<<<dim3(2, 32, 8), 256, 0, stream>>>(encb, w_out, lens, s_part);
    k_cv<<<dim3(32, 8), 128, 0, stream>>>(s_part, Wv, c_ws);
    k_out<<<dim3(8, 32), 128, 0, stream>>>(c_ws, Wo, outp);
}

// Round 4
// 475.723 us; speedup vs baseline: 1.3653x; 1.3278x over previous
//
#include <hip/hip_runtime.h>
#include <stdint.h>

#define T_SEQ   1500
#define NB      32
#define NH      8
#define SCALING 0.08838834764831845f   // 1/sqrt(128)

typedef __attribute__((ext_vector_type(8))) short short8;
typedef __attribute__((ext_vector_type(16))) float floatx16;

__device__ __forceinline__ uint16_t f2bf(float f) {
    uint32_t u = __float_as_uint(f);
    u += 0x7fffu + ((u >> 16) & 1u);   // round-to-nearest-even
    return (uint16_t)(u >> 16);
}
__device__ __forceinline__ float fast_tanh(float x) {
    return 1.f - 2.f / (__expf(2.f * x) + 1.f);
}
// enc_hs_len may arrive as int64 (ref declares jnp.int64) or int32.
__device__ __forceinline__ int get_len(const int* L, int b) {
    return (L[1] == 0) ? L[2 * b] : L[b];
}

// ---------------- enc fp32 -> bf16 (49,152,000 elems, 8/thread) ----------------
__global__ __launch_bounds__(256) void k_conv_enc(const float* __restrict__ in,
                                                  uint16_t* __restrict__ out) {
    int i = blockIdx.x * 256 + threadIdx.x;          // i in [0, 6,144,000)
    const float4* p = (const float4*)in + (size_t)i * 2;
    float4 a = p[0], b = p[1];
    uint4 r;
    r.x = (uint32_t)f2bf(a.x) | ((uint32_t)f2bf(a.y) << 16);
    r.y = (uint32_t)f2bf(a.z) | ((uint32_t)f2bf(a.w) << 16);
    r.z = (uint32_t)f2bf(b.x) | ((uint32_t)f2bf(b.y) << 16);
    r.w = (uint32_t)f2bf(b.z) | ((uint32_t)f2bf(b.w) << 16);
    ((uint4*)out)[i] = r;
}

// --- Wk (h,k,n) fp32 -> Bp: MFMA B-operand-native bf16 layout ---
// Bp[((h*128 + (k>>3))*128 + n)*8 + (k&7)] = Wk[h][k][n]
__global__ __launch_bounds__(128) void k_conv_wkB(const float* __restrict__ Wk,
                                                  uint16_t* __restrict__ Bp) {
    int h = blockIdx.x, g = blockIdx.y;              // g in [0,128)
    int n = threadIdx.x;                             // n in [0,128)
    const float* src = Wk + (size_t)h * 131072 + (size_t)g * 8 * 128 + n;
    uint16_t v[8];
#pragma unroll
    for (int e = 0; e < 8; ++e) v[e] = f2bf(src[(size_t)e * 128]);
    uint4 r;
    r.x = (uint32_t)v[0] | ((uint32_t)v[1] << 16);
    r.y = (uint32_t)v[2] | ((uint32_t)v[3] << 16);
    r.z = (uint32_t)v[4] | ((uint32_t)v[5] << 16);
    r.w = (uint32_t)v[6] | ((uint32_t)v[7] << 16);
    *(uint4*)(Bp + (((size_t)h * 128 + g) * 128 + n) * 8) = r;
}

// ------ q = tanh(dec_z @ Wq + bq); 1 (b,h) per block, K-split x8, 1024 thr ------
// R4: was 128 thr / 1024-long serial FMA chain (latency-bound, 2 waves/CU).
// Now tid = ks*128 + c; thread (ks,c) accumulates d in [128ks,128ks+128) with
// 16-deep unrolled independent strided loads; 8 partials LDS-tree-reduced.
__global__ __launch_bounds__(1024) void k_q(const float* __restrict__ dec_z,
                                            const float* __restrict__ Wq,
                                            const float* __restrict__ bq,
                                            float* __restrict__ q_ws) {
    __shared__ float zs[1024];
    __shared__ float part[8][128];
    int b = blockIdx.x, h = blockIdx.y, tid = threadIdx.x;
    zs[tid] = dec_z[b * 1024 + tid];
    __syncthreads();
    int c = tid & 127, ks = tid >> 7;
    float acc = 0.f;
    const float* wp = Wq + (size_t)h * 131072 + (size_t)ks * 128 * 128 + c;
    const float* zp = zs + ks * 128;
#pragma unroll 16
    for (int d = 0; d < 128; ++d) acc += zp[d] * wp[(size_t)d * 128];
    part[ks][c] = acc;
    __syncthreads();
    if (tid < 128) {
        float a = bq[h * 128 + tid];
#pragma unroll
        for (int k2 = 0; k2 < 8; ++k2) a += part[k2][tid];
        q_ws[(b * 8 + h) * 128 + tid] = fast_tanh(a);
    }
}

// ------- big GEMM: e[b,h,t] = sum_dk tanh( (enc @ Wk[h])[t,dk] ) * q[b,h,dk] -------
// N per head is only 128, so a 128x128 tile re-reads A once per head (8x).
// 2 heads per block (128 rows x 256 cols), 512 thr / 8 waves
// (2 m-halves x 4 n-quarters; head = quarter>>1). A staged ONCE serves both
// heads -> A DMA traffic per FLOP halves. B (2 MB) stays L2-resident per XCD.
//
// LDS swizzle: pair-of-rows XOR. Storage: chunk j=(r&1)*4+u (u = 16B chunk in
// row, k-dir) of row-pair p=r>>1 lives at byte (p*128 + (j^(p&7))*16). For any
// fixed (s,hl) the 32 lanes' ds_read_b128 covers all 32 banks once per 8
// lanes -> conflict-free. global_load_lds writes LINEAR LDS (wave base +
// lane*16), so the permutation is applied to the per-lane GLOBAL source
// address (pre-swizzled source):
//   g=lane>>3, l=lane&7, j=l^g -> row wv*16+2g+(j>>2), chunk u=j&3.
// Per-row 4 chunks stay a contiguous 64B segment -> coalescing preserved.
//
// Pipeline: 4-deep LDS buffers, BK=32; DMA(kt+2) issued at kt, drained by
// counted vmcnt at end of kt+1 (two compute phases + two barriers of cover).
// B prefetched one kt ahead into register dbuf. Raw s_barrier so in-flight
// loads survive.
// vmcnt FIFO (per wave, 5 loads/kt: BLD x4 then DMA x1):
//   end of compute(kt): [D(kt+1)x1, B(kt+1)x4, D(kt+2)x1] -> vmcnt(5)
//   retires exactly D(kt+1). Prologue: [B0x4,D0,D1] -> vmcnt(1). Tail:
//   kt=30 -> vmcnt(4) retires D(31); kt=31 -> nothing (reg-dep retires B).
// Hazards: DMA(kt+2) writes buf[(kt+2)&3], last read compute(kt-2), two
// barriers ago. compute(kt) reads buf[kt&3]: own drain end of kt-1, cross-
// wave visibility via barrier(kt).
__global__ __launch_bounds__(512, 4) void k_gemm_e(const uint16_t* __restrict__ A,   // encb  M x 1024
                                                   const uint16_t* __restrict__ Bp,  // operand-native B
                                                   const float* __restrict__ q_ws,
                                                   float* __restrict__ e_ws) {
    __shared__ uint16_t As[4][128 * 32];   // 32 KB ; buf0 head reused as ered after k-loop

    const int tid = threadIdx.x;
    const int lane = tid & 63, wv = tid >> 6;        // 8 waves
    const int hl = lane >> 5, la = lane & 31;

    // grid: 1504 = 8 XCD-groups x 188; mt in [0,374], hpair in [0,3]
    const int idx = blockIdx.x;
    const int x = idx & 7;
    const int j = idx >> 3;                          // 0..187
    int mt = x * 47 + (j >> 2);
    const int hpair = j & 3;
    if (mt > 374) mt = 374;                          // pad tile: duplicate of 374
    const int m_base = mt * 128;

    const int b0 = m_base / 1500;
    const int b1 = (m_base + 127) / 1500;

    const int wm = wv & 1;                           // m-half
    const int wq = wv >> 1;                          // n-quarter 0..3
    const int h = hpair * 2 + (wq >> 1);             // this wave's head
    const int wn = wq & 1;                           // n-half within head

    // q fragments in registers: cols wn*64 + la and +32, batches b0 and b1
    const int c0 = wn * 64 + la;
    const float* qp0 = q_ws + (b0 * 8 + h) * 128;
    const float* qp1 = q_ws + (b1 * 8 + h) * 128;
    const float q00 = qp0[c0], q01 = qp0[c0 + 32];
    const float q10 = qp1[c0], q11 = qp1[c0 + 32];

    floatx16 acc[2][2];
#pragma unroll
    for (int i = 0; i < 2; ++i)
#pragma unroll
        for (int jj = 0; jj < 2; ++jj)
#pragma unroll
            for (int r = 0; r < 16; ++r) acc[i][jj][r] = 0.f;

    const char* Ab = (const char*)A;
    char* AsB = (char*)As;
    const short8* Bp8 = (const short8*)Bp + (size_t)h * 16384 + wn * 64 + la;

    short8 br[2][2][2];                              // B register double-buffer (32 VGPR)

    // DMA source pre-swizzle (per-lane constants, hoisted):
    const int dg = lane >> 3;                        // 0..7
    const int dj = (lane & 7) ^ dg;                  // chunk permutation
    const int drow = wv * 16 + 2 * dg + (dj >> 2);   // 0..127
    const int du = dj & 3;                           // 16B chunk within kt's 64B
    const char* dma_g0 = Ab + (size_t)(m_base + drow) * 2048 + du * 16;

#define DMA_KT(kt)                                                                   \
    {                                                                                \
        const char* ga = dma_g0 + (kt) * 64;                                         \
        char* ldsa = AsB + ((kt) & 3) * 8192 + wv * 1024;                            \
        __builtin_amdgcn_global_load_lds((const __attribute__((address_space(1))) void*)ga, \
                                         (__attribute__((address_space(3))) void*)ldsa, 16, 0, 0); \
    }
#define BLD_KT(kt)                                                                   \
    {                                                                                \
        _Pragma("unroll")                                                            \
        for (int s = 0; s < 2; ++s) {                                                \
            const short8* bg = Bp8 + (size_t)((kt) * 4 + s * 2 + hl) * 128;          \
            br[(kt) & 1][s][0] = bg[0];                                              \
            br[(kt) & 1][s][1] = bg[32];                                             \
        }                                                                            \
    }

    BLD_KT(0);                                       // oldest in queue
    DMA_KT(0);
    DMA_KT(1);
    __builtin_amdgcn_s_waitcnt(0x0f71);              // vmcnt(1): B(0)+D(0) retired, D(1) in flight

#pragma unroll
    for (int kt = 0; kt < 32; ++kt) {
        __builtin_amdgcn_s_barrier();                // publishes D(kt); in-flight loads survive
        if (kt < 31) BLD_KT(kt + 1);                 // B regs for kt+1 (lazy retire)
        if (kt < 30) DMA_KT(kt + 2);                 // into buf[(kt+2)&3]
#pragma unroll
        for (int s = 0; s < 2; ++s) {                // compute kt
            short8 af[2];
#pragma unroll
            for (int i = 0; i < 2; ++i) {
                int r = wm * 64 + i * 32 + la;       // row this lane reads
                int p = r >> 1;
                int jsl = (((r & 1) << 2) + s * 2 + hl) ^ (p & 7);
                af[i] = *(const short8*)(AsB + (kt & 3) * 8192 + p * 128 + jsl * 16);
            }
#pragma unroll
            for (int i = 0; i < 2; ++i)
#pragma unroll
                for (int jj = 0; jj < 2; ++jj)
                    acc[i][jj] = __builtin_amdgcn_mfma_f32_32x32x16_bf16(af[i], br[kt & 1][s][jj], acc[i][jj], 0, 0, 0);
        }
        if (kt < 30)
            __builtin_amdgcn_s_waitcnt(0x0f75);      // vmcnt(5): retire D(kt+1) only
        else if (kt == 30)
            __builtin_amdgcn_s_waitcnt(0x0f74);      // vmcnt(4): retire D(31)
    }
#undef DMA_KT
#undef BLD_KT

    __syncthreads();                                 // all As reads done; reuse As as ered
    float (*ered)[128][2] = (float(*)[128][2])AsB;   // [head_local][row][wn]

    // epilogue: e_row = sum_col tanh(k) * q[b(row), col]
    // C/D layout 32x32: col = la, row = (rg&3) + 8*(rg>>2) + 4*hl
    const int lim = (b0 + 1) * 1500 - m_base;        // rows >= lim belong to b1
    const int hloc = wq >> 1;
#pragma unroll
    for (int i = 0; i < 2; ++i) {
#pragma unroll
        for (int rg = 0; rg < 16; ++rg) {
            int rowl = wm * 64 + i * 32 + (rg & 3) + 8 * (rg >> 2) + 4 * hl;
            bool second = (rowl >= lim);
            float qa = second ? q10 : q00;
            float qb = second ? q11 : q01;
            float es = fast_tanh(acc[i][0][rg]) * qa + fast_tanh(acc[i][1][rg]) * qb;
            es += __shfl_xor(es, 1);
            es += __shfl_xor(es, 2);
            es += __shfl_xor(es, 4);
            es += __shfl_xor(es, 8);
            es += __shfl_xor(es, 16);
            if (la == 0) ered[hloc][rowl][wn] = es;
        }
    }
    __syncthreads();
    if (tid < 256) {
        int hloc2 = tid >> 7, rowl = tid & 127;
        int rg = m_base + rowl;
        int b = rg / 1500, t = rg - b * 1500;
        e_ws[(b * 8 + hpair * 2 + hloc2) * 1500 + t] = ered[hloc2][rowl][0] + ered[hloc2][rowl][1];
    }
}

// ---------------- masked softmax over t; writes w (an output) ----------------
__global__ __launch_bounds__(256) void k_softmax(const float* __restrict__ e_ws,
                                                 const int* __restrict__ Lp,
                                                 float* __restrict__ w_out) {
    __shared__ float red[4], red2[4];
    int bh = blockIdx.x, tid = threadIdx.x;
    int len = get_len(Lp, bh >> 3);
    const float* e = e_ws + (size_t)bh * 1500;
    float mx = -1e30f;
    for (int t = tid; t < len; t += 256) mx = fmaxf(mx, e[t]);
#pragma unroll
    for (int o = 1; o < 64; o <<= 1) mx = fmaxf(mx, __shfl_xor(mx, o));
    if ((tid & 63) == 0) red[tid >> 6] = mx;
    __syncthreads();
    mx = fmaxf(fmaxf(red[0], red[1]), fmaxf(red[2], red[3]));
    float s = 0.f;
    for (int t = tid; t < len; t += 256) s += __expf(SCALING * (e[t] - mx));
#pragma unroll
    for (int o = 1; o < 64; o <<= 1) s += __shfl_xor(s, o);
    if ((tid & 63) == 0) red2[tid >> 6] = s;
    __syncthreads();
    float inv = 1.f / (red2[0] + red2[1] + red2[2] + red2[3]);
    for (int t = tid; t < 1500; t += 256) {
        float wv = (t < len) ? __expf(SCALING * (e[t] - mx)) * inv : 0.f;
        w_out[(size_t)bh * 1500 + t] = wv;
    }
}

// -------- s[b,h,d] = sum_t w[b,h,t]*enc[b,t,d]; partials over 8 t-parts --------
// R4: 4-deep batched loads in the t-loop (4 independent uint32 loads issued
// before their 64 FMAs) to amortize L3 latency that a serialized
// load->wait->FMA dynamic loop exposes in full.
__global__ __launch_bounds__(256) void k_wsum(const uint16_t* __restrict__ encb,
                                              const float* __restrict__ w,
                                              const int* __restrict__ Lp,
                                              float* __restrict__ s_part) {
    __shared__ float ws_[8][128];
    int dt = blockIdx.x, b = blockIdx.y, p = blockIdx.z;
    int tid = threadIdx.x;
    int len = get_len(Lp, b);
    int t0 = p * 188;
    int t1 = min(min(1500, t0 + 188), len);
    int d0 = (dt * 256 + tid) * 2;
    float a0[8], a1[8];
#pragma unroll
    for (int h = 0; h < 8; ++h) { a0[h] = 0.f; a1[h] = 0.f; }
#define PROCU(u, tl_)                                                        \
    {                                                                        \
        float e0 = __uint_as_float((u) << 16);                               \
        float e1 = __uint_as_float((u) & 0xffff0000u);                       \
        _Pragma("unroll")                                                    \
        for (int hh = 0; hh < 8; ++hh) {                                     \
            float wvv = ws_[hh][tl_];                                        \
            a0[hh] += wvv * e0; a1[hh] += wvv * e1;                          \
        }                                                                    \
    }
    for (int tc = t0; tc < t1; tc += 128) {
        int cl = min(128, t1 - tc);
        __syncthreads();
#pragma unroll
        for (int u = 0; u < 4; ++u) {
            int idx = u * 256 + tid, hh = idx >> 7, tl = idx & 127;
            ws_[hh][tl] = (tl < cl) ? w[(size_t)(b * 8 + hh) * 1500 + tc + tl] : 0.f;
        }
        __syncthreads();
        const uint16_t* ep = encb + ((size_t)b * 1500 + tc) * 1024 + d0;
        int tl = 0;
        for (; tl + 3 < cl; tl += 4) {
            uint32_t u0 = *(const uint32_t*)(ep + (size_t)(tl + 0) * 1024);
            uint32_t u1 = *(const uint32_t*)(ep + (size_t)(tl + 1) * 1024);
            uint32_t u2 = *(const uint32_t*)(ep + (size_t)(tl + 2) * 1024);
            uint32_t u3 = *(const uint32_t*)(ep + (size_t)(tl + 3) * 1024);
            PROCU(u0, tl + 0);
            PROCU(u1, tl + 1);
            PROCU(u2, tl + 2);
            PROCU(u3, tl + 3);
        }
        for (; tl < cl; ++tl) {
            uint32_t u = *(const uint32_t*)(ep + (size_t)tl * 1024);
            PROCU(u, tl);
        }
    }
#undef PROCU
#pragma unroll
    for (int h = 0; h < 8; ++h) {
        float2 v = make_float2(a0[h], a1[h]);
        *(float2*)&s_part[(((size_t)p * 32 + b) * 8 + h) * 1024 + d0] = v;
    }
}

// ------ c[b,h,:] = (sum_p s_part) @ Wv[h]; K-split x8, 1024 thr per (b,h) ------
__global__ __launch_bounds__(1024) void k_cv(const float* __restrict__ s_part,
                                             const float* __restrict__ Wv,
                                             float* __restrict__ c_ws) {
    __shared__ float sv[1024];
    __shared__ float part[8][128];
    int b = blockIdx.x, h = blockIdx.y, tid = threadIdx.x;
    {
        float a = 0.f;
#pragma unroll
        for (int p = 0; p < 8; ++p)
            a += s_part[(((size_t)p * 32 + b) * 8 + h) * 1024 + tid];
        sv[tid] = a;
    }
    __syncthreads();
    int c = tid & 127, ks = tid >> 7;
    float acc = 0.f;
    const float* wp = Wv + (size_t)h * 131072 + (size_t)ks * 128 * 128 + c;
    const float* sp = sv + ks * 128;
#pragma unroll 16
    for (int d = 0; d < 128; ++d) acc += sp[d] * wp[(size_t)d * 128];
    part[ks][c] = acc;
    __syncthreads();
    if (tid < 128) {
        float a = 0.f;
#pragma unroll
        for (int k2 = 0; k2 < 8; ++k2) a += part[k2][tid];
        c_ws[(b * 8 + h) * 128 + tid] = a;
    }
}

// ------ out = c.reshape(B,1024) @ Wo; K-split x8, 1024 thr per (nt,b) ------
__global__ __launch_bounds__(1024) void k_out(const float* __restrict__ c_ws,
                                              const float* __restrict__ Wo,
                                              float* __restrict__ outp) {
    __shared__ float cs[1024];
    __shared__ float part[8][128];
    int nt = blockIdx.x, b = blockIdx.y, tid = threadIdx.x;
    cs[tid] = c_ws[b * 1024 + tid];
    __syncthreads();
    int c = tid & 127, ks = tid >> 7;
    float acc = 0.f;
    const float* wp = Wo + (size_t)(ks * 128) * 1024 + nt * 128 + c;
    const float* cp = cs + ks * 128;
#pragma unroll 16
    for (int m = 0; m < 128; ++m) acc += cp[m] * wp[(size_t)m * 1024];
    part[ks][c] = acc;
    __syncthreads();
    if (tid < 128) {
        float a = 0.f;
#pragma unroll
        for (int k2 = 0; k2 < 8; ++k2) a += part[k2][tid];
        outp[(size_t)b * 1024 + nt * 128 + tid] = a;
    }
}

extern "C" void kernel_launch(void* const* d_in, const int* in_sizes, int n_in,
                              void* d_out, int out_size, void* d_ws, size_t ws_size,
                              hipStream_t stream) {
    const float* enc   = (const float*)d_in[0];
    const int*   lens  = (const int*)d_in[1];
    const float* dec_z = (const float*)d_in[2];
    const float* Wq    = (const float*)d_in[3];
    const float* bq    = (const float*)d_in[4];
    const float* Wk    = (const float*)d_in[5];
    const float* Wv    = (const float*)d_in[6];
    const float* Wo    = (const float*)d_in[7];
    float* outp  = (float*)d_out;           // (32,1024)
    float* w_out = outp + 32768;            // (32,8,1500)

    char* ws = (char*)d_ws;
    uint16_t* encb   = (uint16_t*)ws;                    //  98,304,000 B
    uint16_t* Bp     = (uint16_t*)(ws + 98304000);       //   2,097,152 B
    float*    q_ws   = (float*)(ws + 100401152);         //     131,072 B
    float*    e_ws   = (float*)(ws + 100532224);         //   1,536,000 B
    float*    s_part = (float*)(ws + 102068224);         //   8,388,608 B
    float*    c_ws   = (float*)(ws + 110456832);         //     131,072 B  (end 110,587,904)
    if (ws_size < 110587904) return;

    k_conv_enc<<<24000, 256, 0, stream>>>(enc, encb);
    k_conv_wkB<<<dim3(8, 128), 128, 0, stream>>>(Wk, Bp);
    k_q<<<dim3(32, 8), 1024, 0, stream>>>(dec_z, Wq, bq, q_ws);
    k_gemm_e<<<1504, 512, 0, stream>>>(encb, Bp, q_ws, e_ws);
    k_softmax<<<256, 256, 0, stream>>>(e_ws, lens, w_out);
    k_wsum<<<dim3(2, 32, 8), 256, 0, stream>>>(encb, w_out, lens, s_part);
    k_cv<<<dim3(32, 8), 1024, 0, stream>>>(s_part, Wv, c_ws);
    k_out<<<dim3(8, 32), 1024, 0, stream>>>(c_ws, Wo, outp);
}